// Round 3
// baseline (56.699 us; speedup 1.0000x reference)
//
#include <hip/hip_runtime.h>
#include <hip/hip_cooperative_groups.h>

namespace cg = cooperative_groups;

#define BATCH 4096
#define NUM_CLASSES 10000
#define FEAT_DIM 512
#define GRID 512           // 2 blocks/CU, 8 samples/block
#define SAMPLES_PER_BLOCK (BATCH / GRID)   // 8
#define SAMPLES_PER_WAVE  (SAMPLES_PER_BLOCK / 4)  // 2

// Single cooperative kernel, one graph node.
// Phase 1: each of 512 blocks computes the summed squared distance for its 8
//          samples (one wave handles 2 samples sequentially; each lane covers
//          8 contiguous floats = 2x float4, fully coalesced) -> partial[blk].
// grid.sync()
// Phase 2: block 0 reduces the 512 partials and writes out[0] = sum/BATCH.
// No atomics, no buffer-init dependence: partial is written before read in the
// same call, out[0] is overwritten with '=' every call.
__global__ __launch_bounds__(256) void center_loss_coop(
    const float* __restrict__ x,
    const int* __restrict__ labels,
    const float* __restrict__ centers,
    float* __restrict__ out,
    float* __restrict__ partial)
{
    const int wave = threadIdx.x >> 6;   // 0..3
    const int lane = threadIdx.x & 63;   // 0..63

    float wacc = 0.0f;
    #pragma unroll
    for (int sidx = 0; sidx < SAMPLES_PER_WAVE; ++sidx) {
        const int sample = blockIdx.x * SAMPLES_PER_BLOCK + wave * SAMPLES_PER_WAVE + sidx;
        const int label = labels[sample];   // wave-uniform broadcast load

        const float4* __restrict__ xr = (const float4*)(x + (size_t)sample * FEAT_DIM);
        const float4* __restrict__ cr = (const float4*)(centers + (size_t)label * FEAT_DIM);

        // 512 floats = 128 float4s; 64 lanes x 2 float4 each.
        float4 a0 = xr[lane * 2 + 0];
        float4 a1 = xr[lane * 2 + 1];
        float4 b0 = cr[lane * 2 + 0];
        float4 b1 = cr[lane * 2 + 1];

        float d;
        d = a0.x - b0.x; wacc += d * d;
        d = a0.y - b0.y; wacc += d * d;
        d = a0.z - b0.z; wacc += d * d;
        d = a0.w - b0.w; wacc += d * d;
        d = a1.x - b1.x; wacc += d * d;
        d = a1.y - b1.y; wacc += d * d;
        d = a1.z - b1.z; wacc += d * d;
        d = a1.w - b1.w; wacc += d * d;
    }

    // wave64 butterfly reduce (one tree for both samples' sum)
    #pragma unroll
    for (int off = 32; off > 0; off >>= 1)
        wacc += __shfl_down(wacc, off, 64);

    __shared__ float s[4];
    if (lane == 0) s[wave] = wacc;
    __syncthreads();
    if (threadIdx.x == 0)
        partial[blockIdx.x] = s[0] + s[1] + s[2] + s[3];

    cg::this_grid().sync();

    // Phase 2: block 0 reduces GRID partials (512) with 256 threads.
    if (blockIdx.x == 0) {
        float v = partial[threadIdx.x] + partial[threadIdx.x + 256];
        #pragma unroll
        for (int off = 32; off > 0; off >>= 1)
            v += __shfl_down(v, off, 64);

        __shared__ float s2[4];
        if (lane == 0) s2[wave] = v;
        __syncthreads();
        if (threadIdx.x == 0)
            out[0] = (s2[0] + s2[1] + s2[2] + s2[3]) * (1.0f / (float)BATCH);
    }
}

extern "C" void kernel_launch(void* const* d_in, const int* in_sizes, int n_in,
                              void* d_out, int out_size, void* d_ws, size_t ws_size,
                              hipStream_t stream) {
    const float* x       = (const float*)d_in[0];
    const int*   labels  = (const int*)d_in[1];
    const float* centers = (const float*)d_in[2];
    float* out = (float*)d_out;
    float* partial = (float*)d_ws;   // 512 floats of scratch

    void* args[] = { (void*)&x, (void*)&labels, (void*)&centers,
                     (void*)&out, (void*)&partial };
    hipLaunchCooperativeKernel((const void*)center_loss_coop,
                               dim3(GRID), dim3(256), args, 0, stream);
}

// Round 4
// 11.700 us; speedup vs baseline: 4.8459x; 4.8459x over previous
//
#include <hip/hip_runtime.h>

#define BATCH 4096
#define NUM_CLASSES 10000
#define FEAT_DIM 512

// Kernel 1: one 64-lane wave per sample. Each lane handles 8 contiguous floats
// (2 x float4) of the 512-float row. Per-block (4 samples) partial -> ws.
// (Shape 1024x256 is the best measured so far: R1 = 12.49 us total.)
__global__ __launch_bounds__(256) void center_loss_partial(
    const float* __restrict__ x,
    const int* __restrict__ labels,
    const float* __restrict__ centers,
    float* __restrict__ partial)
{
    const int wave = threadIdx.x >> 6;   // 0..3
    const int lane = threadIdx.x & 63;   // 0..63
    const int sample = blockIdx.x * 4 + wave;   // grid = 1024 -> sample < 4096

    const int label = labels[sample];    // wave-uniform broadcast load

    const float4* __restrict__ xr = (const float4*)(x + (size_t)sample * FEAT_DIM);
    const float4* __restrict__ cr = (const float4*)(centers + (size_t)label * FEAT_DIM);

    // 512 floats = 128 float4s; 64 lanes x 2 float4 each, coalesced.
    float4 a0 = xr[lane * 2 + 0];
    float4 a1 = xr[lane * 2 + 1];
    float4 b0 = cr[lane * 2 + 0];
    float4 b1 = cr[lane * 2 + 1];

    float acc = 0.0f;
    float d;
    d = a0.x - b0.x; acc += d * d;
    d = a0.y - b0.y; acc += d * d;
    d = a0.z - b0.z; acc += d * d;
    d = a0.w - b0.w; acc += d * d;
    d = a1.x - b1.x; acc += d * d;
    d = a1.y - b1.y; acc += d * d;
    d = a1.z - b1.z; acc += d * d;
    d = a1.w - b1.w; acc += d * d;

    // wave64 butterfly reduce
    #pragma unroll
    for (int off = 32; off > 0; off >>= 1)
        acc += __shfl_down(acc, off, 64);

    __shared__ float s[4];
    if (lane == 0) s[wave] = acc;
    __syncthreads();
    if (threadIdx.x == 0)
        partial[blockIdx.x] = s[0] + s[1] + s[2] + s[3];
}

// Kernel 2: one 256-thread block. Each lane loads one float4 of the 1024
// partials (coalesced, one pass), then 2-level shuffle/LDS reduce.
__global__ __launch_bounds__(256) void center_loss_reduce(
    const float* __restrict__ partial,
    float* __restrict__ out)
{
    const int tid  = threadIdx.x;
    const int wave = tid >> 6;
    const int lane = tid & 63;

    float4 p = ((const float4*)partial)[tid];   // 256 x float4 = 1024 floats
    float v = (p.x + p.y) + (p.z + p.w);

    #pragma unroll
    for (int off = 32; off > 0; off >>= 1)
        v += __shfl_down(v, off, 64);

    __shared__ float s[4];
    if (lane == 0) s[wave] = v;
    __syncthreads();
    if (tid == 0)
        out[0] = ((s[0] + s[1]) + (s[2] + s[3])) * (1.0f / (float)BATCH);
}

extern "C" void kernel_launch(void* const* d_in, const int* in_sizes, int n_in,
                              void* d_out, int out_size, void* d_ws, size_t ws_size,
                              hipStream_t stream) {
    const float* x       = (const float*)d_in[0];
    const int*   labels  = (const int*)d_in[1];
    const float* centers = (const float*)d_in[2];
    float* out = (float*)d_out;
    float* partial = (float*)d_ws;   // 1024 floats = 4 KB of scratch

    center_loss_partial<<<BATCH / 4, 256, 0, stream>>>(x, labels, centers, partial);
    center_loss_reduce<<<1, 256, 0, stream>>>(partial, out);
}

// Round 5
// 11.366 us; speedup vs baseline: 4.9883x; 1.0294x over previous
//
#include <hip/hip_runtime.h>

#define BATCH 4096
#define NUM_CLASSES 10000
#define FEAT_DIM 512

// Kernel 1: one 64-lane wave per sample; each lane covers 8 contiguous floats
// (2 x float4). After the 6-step shuffle reduce, lane 0 writes the per-WAVE
// partial directly (no LDS, no __syncthreads) -> 4096 partials.
__global__ __launch_bounds__(256) void center_loss_partial(
    const float* __restrict__ x,
    const int* __restrict__ labels,
    const float* __restrict__ centers,
    float* __restrict__ partial)
{
    const int wave = threadIdx.x >> 6;   // 0..3
    const int lane = threadIdx.x & 63;   // 0..63
    const int sample = blockIdx.x * 4 + wave;   // grid = 1024 -> sample < 4096

    const int label = labels[sample];    // wave-uniform broadcast load

    const float4* __restrict__ xr = (const float4*)(x + (size_t)sample * FEAT_DIM);
    const float4* __restrict__ cr = (const float4*)(centers + (size_t)label * FEAT_DIM);

    // 512 floats = 128 float4s; 64 lanes x 2 float4 each, coalesced.
    float4 a0 = xr[lane * 2 + 0];
    float4 a1 = xr[lane * 2 + 1];
    float4 b0 = cr[lane * 2 + 0];
    float4 b1 = cr[lane * 2 + 1];

    float acc = 0.0f;
    float d;
    d = a0.x - b0.x; acc += d * d;
    d = a0.y - b0.y; acc += d * d;
    d = a0.z - b0.z; acc += d * d;
    d = a0.w - b0.w; acc += d * d;
    d = a1.x - b1.x; acc += d * d;
    d = a1.y - b1.y; acc += d * d;
    d = a1.z - b1.z; acc += d * d;
    d = a1.w - b1.w; acc += d * d;

    // wave64 butterfly reduce
    #pragma unroll
    for (int off = 32; off > 0; off >>= 1)
        acc += __shfl_down(acc, off, 64);

    if (lane == 0)
        partial[sample] = acc;   // sample == blockIdx.x*4 + wave
}

// Kernel 2: one 256-thread block. Each thread loads 4 float4s of the 4096
// partials (one coalesced pass, 16 KB), then shuffle/LDS reduce.
__global__ __launch_bounds__(256) void center_loss_reduce(
    const float* __restrict__ partial,
    float* __restrict__ out)
{
    const int tid  = threadIdx.x;
    const int wave = tid >> 6;
    const int lane = tid & 63;

    const float4* p4 = (const float4*)partial;   // 1024 float4s
    float4 p0 = p4[tid];
    float4 p1 = p4[tid + 256];
    float4 p2 = p4[tid + 512];
    float4 p3 = p4[tid + 768];

    float v = ((p0.x + p0.y) + (p0.z + p0.w))
            + ((p1.x + p1.y) + (p1.z + p1.w))
            + ((p2.x + p2.y) + (p2.z + p2.w))
            + ((p3.x + p3.y) + (p3.z + p3.w));

    #pragma unroll
    for (int off = 32; off > 0; off >>= 1)
        v += __shfl_down(v, off, 64);

    __shared__ float s[4];
    if (lane == 0) s[wave] = v;
    __syncthreads();
    if (tid == 0)
        out[0] = ((s[0] + s[1]) + (s[2] + s[3])) * (1.0f / (float)BATCH);
}

extern "C" void kernel_launch(void* const* d_in, const int* in_sizes, int n_in,
                              void* d_out, int out_size, void* d_ws, size_t ws_size,
                              hipStream_t stream) {
    const float* x       = (const float*)d_in[0];
    const int*   labels  = (const int*)d_in[1];
    const float* centers = (const float*)d_in[2];
    float* out = (float*)d_out;
    float* partial = (float*)d_ws;   // 4096 floats = 16 KB of scratch

    center_loss_partial<<<BATCH / 4, 256, 0, stream>>>(x, labels, centers, partial);
    center_loss_reduce<<<1, 256, 0, stream>>>(partial, out);
}

// Round 6
// 11.242 us; speedup vs baseline: 5.0435x; 1.0111x over previous
//
#include <hip/hip_runtime.h>

#define BATCH 4096
#define NUM_CLASSES 10000
#define FEAT_DIM 512

// Kernel 1: one 64-lane wave per sample; lane i covers float4 #i and #(i+64)
// of the 128-float4 row (blocked split: each load instruction spans one fully
// contiguous 1KB segment). After the 6-step shuffle reduce, lane 0 writes the
// per-wave partial directly (no LDS, no __syncthreads) -> 4096 partials.
__global__ __launch_bounds__(256) void center_loss_partial(
    const float* __restrict__ x,
    const int* __restrict__ labels,
    const float* __restrict__ centers,
    float* __restrict__ partial)
{
    const int wave = threadIdx.x >> 6;   // 0..3
    const int lane = threadIdx.x & 63;   // 0..63
    const int sample = blockIdx.x * 4 + wave;   // grid = 1024 -> sample < 4096

    const int label = labels[sample];    // wave-uniform broadcast load

    const float4* __restrict__ xr = (const float4*)(x + (size_t)sample * FEAT_DIM);
    const float4* __restrict__ cr = (const float4*)(centers + (size_t)label * FEAT_DIM);

    float4 a0 = xr[lane];
    float4 a1 = xr[lane + 64];
    float4 b0 = cr[lane];
    float4 b1 = cr[lane + 64];

    float acc = 0.0f;
    float d;
    d = a0.x - b0.x; acc += d * d;
    d = a0.y - b0.y; acc += d * d;
    d = a0.z - b0.z; acc += d * d;
    d = a0.w - b0.w; acc += d * d;
    d = a1.x - b1.x; acc += d * d;
    d = a1.y - b1.y; acc += d * d;
    d = a1.z - b1.z; acc += d * d;
    d = a1.w - b1.w; acc += d * d;

    // wave64 butterfly reduce
    #pragma unroll
    for (int off = 32; off > 0; off >>= 1)
        acc += __shfl_down(acc, off, 64);

    if (lane == 0)
        partial[sample] = acc;
}

// Kernel 2: ONE wave (64 threads). Each lane loads 16 float4s of the 4096
// partials (independent, coalesced -> one latency round trip), adds, then a
// pure shuffle reduce. No LDS, no __syncthreads.
__global__ __launch_bounds__(64) void center_loss_reduce(
    const float* __restrict__ partial,
    float* __restrict__ out)
{
    const int lane = threadIdx.x;
    const float4* p4 = (const float4*)partial;   // 1024 float4s

    float4 r[16];
    #pragma unroll
    for (int k = 0; k < 16; ++k)
        r[k] = p4[lane + k * 64];

    float v = 0.0f;
    #pragma unroll
    for (int k = 0; k < 16; ++k)
        v += ((r[k].x + r[k].y) + (r[k].z + r[k].w));

    #pragma unroll
    for (int off = 32; off > 0; off >>= 1)
        v += __shfl_down(v, off, 64);

    if (lane == 0)
        out[0] = v * (1.0f / (float)BATCH);
}

extern "C" void kernel_launch(void* const* d_in, const int* in_sizes, int n_in,
                              void* d_out, int out_size, void* d_ws, size_t ws_size,
                              hipStream_t stream) {
    const float* x       = (const float*)d_in[0];
    const int*   labels  = (const int*)d_in[1];
    const float* centers = (const float*)d_in[2];
    float* out = (float*)d_out;
    float* partial = (float*)d_ws;   // 4096 floats = 16 KB of scratch

    center_loss_partial<<<BATCH / 4, 256, 0, stream>>>(x, labels, centers, partial);
    center_loss_reduce<<<1, 64, 0, stream>>>(partial, out);
}